// Round 18
// baseline (434.295 us; speedup 1.0000x reference)
//
#include <hip/hip_runtime.h>
#include <hip/hip_bf16.h>
#include <type_traits>

#define BQ   256
#define NTR  50000
#define DD   3072
#define NSP  50048          // padded N stride (multiple of 64)
#define NBLK 782
#define CAP  4096
#define DELTA 18.0f

typedef __fp16 f16;
typedef __fp16 f16x2 __attribute__((ext_vector_type(2)));
typedef __fp16 f16x4 __attribute__((ext_vector_type(4)));
typedef __fp16 f16x8 __attribute__((ext_vector_type(8)));
typedef float  f32x4 __attribute__((ext_vector_type(4)));

// ---------------- P0: convert x (f32) -> fp16, fragment-major pack ----------------
__global__ __launch_bounds__(256) void kx(const float* __restrict__ x, f16* __restrict__ xp) {
    const int t = blockIdx.x * 256 + threadIdx.x;   // t = g*256 + r, grid = 384*256
    const int g = t >> 8, r = t & 255;
    const f32x4* src = (const f32x4*)(x + (size_t)r * DD + (g << 3));
    f32x4 a = src[0], b = src[1];
    union { f16x2 h2[4]; f16x8 h8; } u;
    u.h2[0] = __builtin_amdgcn_cvt_pkrtz(a[0], a[1]);
    u.h2[1] = __builtin_amdgcn_cvt_pkrtz(a[2], a[3]);
    u.h2[2] = __builtin_amdgcn_cvt_pkrtz(b[0], b[1]);
    u.h2[3] = __builtin_amdgcn_cvt_pkrtz(b[2], b[3]);
    ((f16x8*)xp)[t] = u.h8;
}

// ---------------- P1: r16-exact kqk (launched TWICE this round: measurement) ----------------
__global__ __launch_bounds__(512, 4) void kqk(
    const f16* __restrict__ xp, const float* __restrict__ y,
    f16* __restrict__ S, float* __restrict__ pmax) {
    __shared__ char Bs[2][8192];   // 64 rows x 128 B (fp16), XOR-swizzled

    const int tid = threadIdx.x;
    // XCD-chunked bijective swizzle (782 = 6*98 + 2*97)
    const int orig = blockIdx.x;
    const int xcd = orig & 7, cidx = orig >> 3;
    const int blk = (xcd < 6 ? xcd * 98 : 588 + (xcd - 6) * 97) + cidx;
    const int n0  = blk * 64;

    // y staging: 16 threads/row, 16B each; thread covers rows ry0 and ry0+32
    const int ry0 = tid >> 4;             // 0..31
    const int kc  = tid & 15;             // 16B chunk within the 256B row-step
    const int yr0 = n0 + ry0, yr1 = yr0 + 32;
    const bool yv0 = yr0 < NTR, yv1 = yr1 < NTR;
    const float* yb0 = y + (size_t)yr0 * DD + (kc << 2);
    const float* yb1 = y + (size_t)yr1 * DD + (kc << 2);
    const int swz = (ry0 & 7) << 4;       // (ry0+32)&7 == ry0&7
    const int bo0 = ry0 * 128        + (((((kc >> 1) << 4)) ^ swz) | ((kc & 1) << 3));
    const int bo1 = (ry0 + 32) * 128 + (((((kc >> 1) << 4)) ^ swz) | ((kc & 1) << 3));

    const int w = tid >> 6, l = tid & 63;   // w = 0..7
    const int l15 = l & 15, lg = l >> 4;

    f32x4 acc[2][4] = {};
    float y2a0 = 0.f, y2a1 = 0.f;
    f32x4 p0, p1, q0, q1;

    auto loady = [&](f32x4& a0, f32x4& a1, int ks) {
        a0 = yv0 ? *(const f32x4*)(yb0 + (ks << 6)) : f32x4(0.f);
        a1 = yv1 ? *(const f32x4*)(yb1 + (ks << 6)) : f32x4(0.f);
    };
    auto cvtw = [&](f32x4& a0, f32x4& a1, int buf) {
        y2a0 += a0[0]*a0[0] + a0[1]*a0[1] + a0[2]*a0[2] + a0[3]*a0[3];
        y2a1 += a1[0]*a1[0] + a1[1]*a1[1] + a1[2]*a1[2] + a1[3]*a1[3];
        union { f16x2 h2[2]; f16x4 h4; } u0, u1;
        u0.h2[0] = __builtin_amdgcn_cvt_pkrtz(a0[0], a0[1]);
        u0.h2[1] = __builtin_amdgcn_cvt_pkrtz(a0[2], a0[3]);
        u1.h2[0] = __builtin_amdgcn_cvt_pkrtz(a1[0], a1[1]);
        u1.h2[1] = __builtin_amdgcn_cvt_pkrtz(a1[2], a1[3]);
        *(f16x4*)(&Bs[buf][bo0]) = u0.h4;
        *(f16x4*)(&Bs[buf][bo1]) = u1.h4;
    };

    // prologue: y(0)->Bs[0], y(1) in Q
    loady(p0, p1, 0);
    loady(q0, q1, 1);
    cvtw(p0, p1, 0);
    asm volatile("s_waitcnt lgkmcnt(0)" ::: "memory");
    __builtin_amdgcn_s_barrier();

    const f16x8* ap = (const f16x8*)xp;
    const int arow = (w << 5) + l15;        // wave w owns query rows w*32..w*32+31

    auto iter = [&](int ks, auto curC,
                    f32x4& s0, f32x4& s1,      // prefetch slot (y(ks+2))
                    f32x4& t0, f32x4& t1) {    // cvt slot (y(ks+1))
        constexpr int cur = decltype(curC)::value;
        f16x8 af[2][2];
        #pragma unroll
        for (int kk = 0; kk < 2; ++kk)
            #pragma unroll
            for (int fm = 0; fm < 2; ++fm)
                af[kk][fm] = ap[(size_t)((ks << 3) + (kk << 2) + lg) * 256 + arow + (fm << 4)];
        if (ks + 2 < 48) loady(s0, s1, ks + 2);
        f16x8 bf[2][4];
        #pragma unroll
        for (int kk = 0; kk < 2; ++kk)
            #pragma unroll
            for (int fn = 0; fn < 4; ++fn) {
                int r = (fn << 4) + l15;
                bf[kk][fn] = *(const f16x8*)(&Bs[cur][r * 128 + (((kk << 6) + (lg << 4)) ^ ((r & 7) << 4))]);
            }
        #pragma unroll
        for (int kk = 0; kk < 2; ++kk)
            #pragma unroll
            for (int fm = 0; fm < 2; ++fm)
                #pragma unroll
                for (int fn = 0; fn < 4; ++fn)
                    acc[fm][fn] = __builtin_amdgcn_mfma_f32_16x16x32_f16(af[kk][fm], bf[kk][fn], acc[fm][fn], 0, 0, 0);
        if (ks + 1 < 48) cvtw(t0, t1, cur ^ 1);
        asm volatile("s_waitcnt lgkmcnt(0)" ::: "memory");
        __builtin_amdgcn_s_barrier();
    };

    for (int ks2 = 0; ks2 < 48; ks2 += 2) {
        iter(ks2,     std::integral_constant<int,0>{}, p0, p1, q0, q1);
        iter(ks2 + 1, std::integral_constant<int,1>{}, q0, q1, p0, p1);
    }

    // epilogue: y2 per row (16 threads/row, 2 rows/thread) -> LDS broadcast
    float* lys = (float*)&Bs[0][0];
    #pragma unroll
    for (int off = 1; off < 16; off <<= 1) {
        y2a0 += __shfl_xor(y2a0, off, 64);
        y2a1 += __shfl_xor(y2a1, off, 64);
    }
    if ((tid & 15) == 0) { lys[ry0] = y2a0; lys[ry0 + 32] = y2a1; }
    __syncthreads();
    float ly2[4];
    #pragma unroll
    for (int fn = 0; fn < 4; ++fn) ly2[fn] = 0.5f * lys[(fn << 4) + l15];
    // per-row max over this block's 64 cols (pad cols masked)
    #pragma unroll
    for (int fm = 0; fm < 2; ++fm) {
        #pragma unroll
        for (int j = 0; j < 4; ++j) {
            float rm = -3.4e38f;
            #pragma unroll
            for (int fn = 0; fn < 4; ++fn) {
                int col = n0 + (fn << 4) + l15;
                float sc = acc[fm][fn][j] - ly2[fn];
                rm = (col < NTR) ? fmaxf(rm, sc) : rm;
            }
            #pragma unroll
            for (int off = 1; off < 16; off <<= 1) rm = fmaxf(rm, __shfl_xor(rm, off, 64));
            if (l15 == 0)
                pmax[(size_t)((w << 5) + (fm << 4) + (lg << 2) + j) * NBLK + blk] = rm;
        }
    }
    // S = x.y - 0.5|y|^2, stored fp16 (selection-only; exact rescore happens in ksp)
    #pragma unroll
    for (int fm = 0; fm < 2; ++fm) {
        int row0 = (w << 5) + (fm << 4) + (lg << 2);
        #pragma unroll
        for (int fn = 0; fn < 4; ++fn) {
            int col = n0 + (fn << 4) + l15;
            f16* sp = S + (size_t)row0 * NSP + col;
            sp[0]               = (f16)(acc[fm][fn][0] - ly2[fn]);
            sp[NSP]             = (f16)(acc[fm][fn][1] - ly2[fn]);
            sp[2 * (size_t)NSP] = (f16)(acc[fm][fn][2] - ly2[fn]);
            sp[3 * (size_t)NSP] = (f16)(acc[fm][fn][3] - ly2[fn]);
        }
    }
}

// ---------------- P2+P3 fused: max -> scan fp16 S -> exact rescore + online softmax + PV ----------------
__global__ __launch_bounds__(512) void ksp(
    const float* __restrict__ x, const float* __restrict__ y,
    const f16* __restrict__ S, const float* __restrict__ pmax,
    const float* __restrict__ sig, float* __restrict__ out) {
    __shared__ float xs[DD];
    __shared__ unsigned ci[CAP];
    __shared__ unsigned scnt;
    __shared__ float red[8];
    __shared__ float om[8], ol[8];
    __shared__ float sumv[DD];
    const int b = blockIdx.x, tid = threadIdx.x;
    const float s2 = sig[b] * sig[b];
    const float isc = -0.5f / s2;
    const int w = tid >> 6, l = tid & 63;

    if (tid == 0) scnt = 0;
    for (int i = tid; i < DD; i += 512) xs[i] = x[(size_t)b * DD + i];
    const float* pm = pmax + (size_t)b * NBLK;
    float mx = -3.4e38f;
    for (int i = tid; i < NBLK; i += 512) mx = fmaxf(mx, pm[i]);
    #pragma unroll
    for (int o = 1; o < 64; o <<= 1) mx = fmaxf(mx, __shfl_xor(mx, o, 64));
    if (l == 0) red[w] = mx;
    __syncthreads();
    mx = red[0];
    #pragma unroll
    for (int ww = 1; ww < 8; ++ww) mx = fmaxf(mx, red[ww]);
    const float thr = mx - DELTA * s2 - 2.0f;   // fp16-S safety margin

    const f16x8* row = (const f16x8*)(S + (size_t)b * NSP);
    for (int i = tid; i < 6256; i += 512) {      // 6256*8 = 50048
        f16x8 v = row[i];
        #pragma unroll
        for (int j = 0; j < 8; ++j) {
            int idx = (i << 3) + j;
            if ((float)v[j] >= thr && idx < NTR) {
                unsigned p = atomicAdd(&scnt, 1u);
                if (p < CAP) ci[p] = (unsigned)idx;
            }
        }
    }
    __syncthreads();
    const int c = (int)(scnt < (unsigned)CAP ? scnt : (unsigned)CAP);

    const f32x4* xr = (const f32x4*)xs;
    f32x4 o[12] = {};
    float m = -3.4e38f, ll = 0.f;
    f32x4 A[12], Bv[12];

    auto LD = [&](f32x4* dst, int i) {
        const f32x4* yr = (const f32x4*)(y + (size_t)ci[i] * DD);
        #pragma unroll
        for (int j = 0; j < 12; ++j) dst[j] = yr[(j << 6) + l];
    };
    auto PROC = [&](f32x4* src) {
        float d2 = 0.f;
        #pragma unroll
        for (int j = 0; j < 12; ++j) {
            f32x4 xv = xr[(j << 6) + l];
            float a0 = xv[0]-src[j][0], a1 = xv[1]-src[j][1],
                  a2 = xv[2]-src[j][2], a3 = xv[3]-src[j][3];
            d2 += a0*a0 + a1*a1 + a2*a2 + a3*a3;
        }
        #pragma unroll
        for (int off = 1; off < 64; off <<= 1) d2 += __shfl_xor(d2, off, 64);
        float s = d2 * isc;
        float mn = fmaxf(m, s);
        float f = __expf(m - mn);
        float wi = __expf(s - mn);
        #pragma unroll
        for (int j = 0; j < 12; ++j) o[j] = o[j] * f + wi * src[j];
        ll = ll * f + wi;
        m = mn;
    };

    int i = w;
    if (i < c) LD(A, i);
    for (; i < c; i += 16) {
        int i2 = i + 8;
        if (i2 < c) LD(Bv, i2);
        PROC(A);
        if (i2 < c) {
            if (i + 16 < c) LD(A, i + 16);
            PROC(Bv);
        }
    }
    om[w] = m; ol[w] = ll;
    __syncthreads();
    float M = om[0];
    #pragma unroll
    for (int ww = 1; ww < 8; ++ww) M = fmaxf(M, om[ww]);
    float Ls = 0.f;
    #pragma unroll
    for (int ww = 0; ww < 8; ++ww) Ls += ol[ww] * __expf(om[ww] - M);
    const float fw = __expf(m - M);
    f32x4* sv = (f32x4*)sumv;
    if (w == 0) {
        #pragma unroll
        for (int j = 0; j < 12; ++j) sv[(j << 6) + l] = o[j] * fw;
    }
    __syncthreads();
    for (int ww = 1; ww < 8; ++ww) {
        if (w == ww) {
            #pragma unroll
            for (int j = 0; j < 12; ++j) sv[(j << 6) + l] += o[j] * fw;
        }
        __syncthreads();
    }
    const float inv = 1.f / Ls;
    f32x4* od = (f32x4*)(out + (size_t)b * DD);
    for (int t = tid; t < 768; t += 512) od[t] = sv[t] * inv;
}

extern "C" void kernel_launch(void* const* d_in, const int* in_sizes, int n_in,
                              void* d_out, int out_size, void* d_ws, size_t ws_size,
                              hipStream_t stream) {
    const float* x   = (const float*)d_in[0];
    const float* sig = (const float*)d_in[1];
    const float* y   = (const float*)d_in[2];
    float* out = (float*)d_out;
    char* ws = (char*)d_ws;
    f16*   xp   = (f16*)(ws);                   // 1,572,864
    float* pmax = (float*)(ws + 1572864);       // 256*782*4 = 800,768
    f16*   S    = (f16*)(ws + 2373632);         // 256*50048*2 = 25,624,576

    kx  <<<384, 256, 0, stream>>>(x, xp);
    // MEASUREMENT ROUND: kqk twice (idempotent) so its dispatches rank above the
    // harness poison-fills and get full PMC. T_kqk = dur of each kqk dispatch.
    kqk <<<NBLK, 512, 0, stream>>>(xp, y, S, pmax);
    kqk <<<NBLK, 512, 0, stream>>>(xp, y, S, pmax);
    ksp <<<256, 512, 0, stream>>>(x, y, S, pmax, sig, out);
}

// Round 19
// 243.915 us; speedup vs baseline: 1.7805x; 1.7805x over previous
//
#include <hip/hip_runtime.h>
#include <hip/hip_bf16.h>
#include <type_traits>

#define BQ   256
#define NTR  50000
#define DD   3072
#define NSP  50048          // padded N stride (multiple of 64)
#define NBLK 782
#define CAP  4096
#define DELTA 18.0f

typedef __fp16 f16;
typedef __fp16 f16x2 __attribute__((ext_vector_type(2)));
typedef __fp16 f16x4 __attribute__((ext_vector_type(4)));
typedef __fp16 f16x8 __attribute__((ext_vector_type(8)));
typedef float  f32x4 __attribute__((ext_vector_type(4)));

// ---------------- P0: convert x (f32) -> fp16, fragment-major pack ----------------
__global__ __launch_bounds__(256) void kx(const float* __restrict__ x, f16* __restrict__ xp) {
    const int t = blockIdx.x * 256 + threadIdx.x;   // t = g*256 + r, grid = 384*256
    const int g = t >> 8, r = t & 255;
    const f32x4* src = (const f32x4*)(x + (size_t)r * DD + (g << 3));
    f32x4 a = src[0], b = src[1];
    union { f16x2 h2[4]; f16x8 h8; } u;
    u.h2[0] = __builtin_amdgcn_cvt_pkrtz(a[0], a[1]);
    u.h2[1] = __builtin_amdgcn_cvt_pkrtz(a[2], a[3]);
    u.h2[2] = __builtin_amdgcn_cvt_pkrtz(b[0], b[1]);
    u.h2[3] = __builtin_amdgcn_cvt_pkrtz(b[2], b[3]);
    ((f16x8*)xp)[t] = u.h8;
}

// ---------------- P1: S = X*Y^T - 0.5*|y|^2 (champion: r16 structure) ----------------
__global__ __launch_bounds__(512, 4) void kqk(
    const f16* __restrict__ xp, const float* __restrict__ y,
    f16* __restrict__ S, float* __restrict__ pmax) {
    __shared__ char Bs[2][8192];   // 64 rows x 128 B (fp16), XOR-swizzled

    const int tid = threadIdx.x;
    // XCD-chunked bijective swizzle (782 = 6*98 + 2*97)
    const int orig = blockIdx.x;
    const int xcd = orig & 7, cidx = orig >> 3;
    const int blk = (xcd < 6 ? xcd * 98 : 588 + (xcd - 6) * 97) + cidx;
    const int n0  = blk * 64;

    // y staging: 16 threads/row, 16B each; thread covers rows ry0 and ry0+32
    const int ry0 = tid >> 4;             // 0..31
    const int kc  = tid & 15;             // 16B chunk within the 256B row-step
    const int yr0 = n0 + ry0, yr1 = yr0 + 32;
    const bool yv0 = yr0 < NTR, yv1 = yr1 < NTR;
    const float* yb0 = y + (size_t)yr0 * DD + (kc << 2);
    const float* yb1 = y + (size_t)yr1 * DD + (kc << 2);
    const int swz = (ry0 & 7) << 4;       // (ry0+32)&7 == ry0&7
    const int bo0 = ry0 * 128        + (((((kc >> 1) << 4)) ^ swz) | ((kc & 1) << 3));
    const int bo1 = (ry0 + 32) * 128 + (((((kc >> 1) << 4)) ^ swz) | ((kc & 1) << 3));

    const int w = tid >> 6, l = tid & 63;   // w = 0..7
    const int l15 = l & 15, lg = l >> 4;

    f32x4 acc[2][4] = {};
    float y2a0 = 0.f, y2a1 = 0.f;
    f32x4 p0, p1, q0, q1;

    auto loady = [&](f32x4& a0, f32x4& a1, int ks) {
        a0 = yv0 ? *(const f32x4*)(yb0 + (ks << 6)) : f32x4(0.f);
        a1 = yv1 ? *(const f32x4*)(yb1 + (ks << 6)) : f32x4(0.f);
    };
    auto cvtw = [&](f32x4& a0, f32x4& a1, int buf) {
        y2a0 += a0[0]*a0[0] + a0[1]*a0[1] + a0[2]*a0[2] + a0[3]*a0[3];
        y2a1 += a1[0]*a1[0] + a1[1]*a1[1] + a1[2]*a1[2] + a1[3]*a1[3];
        union { f16x2 h2[2]; f16x4 h4; } u0, u1;
        u0.h2[0] = __builtin_amdgcn_cvt_pkrtz(a0[0], a0[1]);
        u0.h2[1] = __builtin_amdgcn_cvt_pkrtz(a0[2], a0[3]);
        u1.h2[0] = __builtin_amdgcn_cvt_pkrtz(a1[0], a1[1]);
        u1.h2[1] = __builtin_amdgcn_cvt_pkrtz(a1[2], a1[3]);
        *(f16x4*)(&Bs[buf][bo0]) = u0.h4;
        *(f16x4*)(&Bs[buf][bo1]) = u1.h4;
    };

    // prologue: y(0)->Bs[0], y(1) in Q
    loady(p0, p1, 0);
    loady(q0, q1, 1);
    cvtw(p0, p1, 0);
    asm volatile("s_waitcnt lgkmcnt(0)" ::: "memory");
    __builtin_amdgcn_s_barrier();

    const f16x8* ap = (const f16x8*)xp;
    const int arow = (w << 5) + l15;        // wave w owns query rows w*32..w*32+31

    auto iter = [&](int ks, auto curC,
                    f32x4& s0, f32x4& s1,      // prefetch slot (y(ks+2))
                    f32x4& t0, f32x4& t1) {    // cvt slot (y(ks+1))
        constexpr int cur = decltype(curC)::value;
        f16x8 af[2][2];
        #pragma unroll
        for (int kk = 0; kk < 2; ++kk)
            #pragma unroll
            for (int fm = 0; fm < 2; ++fm)
                af[kk][fm] = ap[(size_t)((ks << 3) + (kk << 2) + lg) * 256 + arow + (fm << 4)];
        if (ks + 2 < 48) loady(s0, s1, ks + 2);
        f16x8 bf[2][4];
        #pragma unroll
        for (int kk = 0; kk < 2; ++kk)
            #pragma unroll
            for (int fn = 0; fn < 4; ++fn) {
                int r = (fn << 4) + l15;
                bf[kk][fn] = *(const f16x8*)(&Bs[cur][r * 128 + (((kk << 6) + (lg << 4)) ^ ((r & 7) << 4))]);
            }
        #pragma unroll
        for (int kk = 0; kk < 2; ++kk)
            #pragma unroll
            for (int fm = 0; fm < 2; ++fm)
                #pragma unroll
                for (int fn = 0; fn < 4; ++fn)
                    acc[fm][fn] = __builtin_amdgcn_mfma_f32_16x16x32_f16(af[kk][fm], bf[kk][fn], acc[fm][fn], 0, 0, 0);
        if (ks + 1 < 48) cvtw(t0, t1, cur ^ 1);
        asm volatile("s_waitcnt lgkmcnt(0)" ::: "memory");
        __builtin_amdgcn_s_barrier();
    };

    for (int ks2 = 0; ks2 < 48; ks2 += 2) {
        iter(ks2,     std::integral_constant<int,0>{}, p0, p1, q0, q1);
        iter(ks2 + 1, std::integral_constant<int,1>{}, q0, q1, p0, p1);
    }

    // epilogue: y2 per row (16 threads/row, 2 rows/thread) -> LDS broadcast
    float* lys = (float*)&Bs[0][0];
    #pragma unroll
    for (int off = 1; off < 16; off <<= 1) {
        y2a0 += __shfl_xor(y2a0, off, 64);
        y2a1 += __shfl_xor(y2a1, off, 64);
    }
    if ((tid & 15) == 0) { lys[ry0] = y2a0; lys[ry0 + 32] = y2a1; }
    __syncthreads();
    float ly2[4];
    #pragma unroll
    for (int fn = 0; fn < 4; ++fn) ly2[fn] = 0.5f * lys[(fn << 4) + l15];
    // per-row max over this block's 64 cols (pad cols masked)
    #pragma unroll
    for (int fm = 0; fm < 2; ++fm) {
        #pragma unroll
        for (int j = 0; j < 4; ++j) {
            float rm = -3.4e38f;
            #pragma unroll
            for (int fn = 0; fn < 4; ++fn) {
                int col = n0 + (fn << 4) + l15;
                float sc = acc[fm][fn][j] - ly2[fn];
                rm = (col < NTR) ? fmaxf(rm, sc) : rm;
            }
            #pragma unroll
            for (int off = 1; off < 16; off <<= 1) rm = fmaxf(rm, __shfl_xor(rm, off, 64));
            if (l15 == 0)
                pmax[(size_t)((w << 5) + (fm << 4) + (lg << 2) + j) * NBLK + blk] = rm;
        }
    }
    // S = x.y - 0.5|y|^2, stored fp16 (selection-only; exact rescore happens in ksp)
    #pragma unroll
    for (int fm = 0; fm < 2; ++fm) {
        int row0 = (w << 5) + (fm << 4) + (lg << 2);
        #pragma unroll
        for (int fn = 0; fn < 4; ++fn) {
            int col = n0 + (fn << 4) + l15;
            f16* sp = S + (size_t)row0 * NSP + col;
            sp[0]               = (f16)(acc[fm][fn][0] - ly2[fn]);
            sp[NSP]             = (f16)(acc[fm][fn][1] - ly2[fn]);
            sp[2 * (size_t)NSP] = (f16)(acc[fm][fn][2] - ly2[fn]);
            sp[3 * (size_t)NSP] = (f16)(acc[fm][fn][3] - ly2[fn]);
        }
    }
}

// ---------------- P2+P3 fused: max -> scan fp16 S -> exact rescore + online softmax + PV ----------------
__global__ __launch_bounds__(512) void ksp(
    const float* __restrict__ x, const float* __restrict__ y,
    const f16* __restrict__ S, const float* __restrict__ pmax,
    const float* __restrict__ sig, float* __restrict__ out) {
    __shared__ float xs[DD];
    __shared__ unsigned ci[CAP];
    __shared__ unsigned scnt;
    __shared__ float red[8];
    __shared__ float om[8], ol[8];
    __shared__ float sumv[DD];
    const int b = blockIdx.x, tid = threadIdx.x;
    const float s2 = sig[b] * sig[b];
    const float isc = -0.5f / s2;
    const int w = tid >> 6, l = tid & 63;

    if (tid == 0) scnt = 0;
    for (int i = tid; i < DD; i += 512) xs[i] = x[(size_t)b * DD + i];
    const float* pm = pmax + (size_t)b * NBLK;
    float mx = -3.4e38f;
    for (int i = tid; i < NBLK; i += 512) mx = fmaxf(mx, pm[i]);
    #pragma unroll
    for (int o = 1; o < 64; o <<= 1) mx = fmaxf(mx, __shfl_xor(mx, o, 64));
    if (l == 0) red[w] = mx;
    __syncthreads();
    mx = red[0];
    #pragma unroll
    for (int ww = 1; ww < 8; ++ww) mx = fmaxf(mx, red[ww]);
    const float thr = mx - DELTA * s2 - 2.0f;   // fp16-S safety margin

    const f16x8* row = (const f16x8*)(S + (size_t)b * NSP);
    for (int i = tid; i < 6256; i += 512) {      // 6256*8 = 50048
        f16x8 v = row[i];
        #pragma unroll
        for (int j = 0; j < 8; ++j) {
            int idx = (i << 3) + j;
            if ((float)v[j] >= thr && idx < NTR) {
                unsigned p = atomicAdd(&scnt, 1u);
                if (p < CAP) ci[p] = (unsigned)idx;
            }
        }
    }
    __syncthreads();
    const int c = (int)(scnt < (unsigned)CAP ? scnt : (unsigned)CAP);

    const f32x4* xr = (const f32x4*)xs;
    f32x4 o[12] = {};
    float m = -3.4e38f, ll = 0.f;
    f32x4 A[12], Bv[12];

    auto LD = [&](f32x4* dst, int i) {
        const f32x4* yr = (const f32x4*)(y + (size_t)ci[i] * DD);
        #pragma unroll
        for (int j = 0; j < 12; ++j) dst[j] = yr[(j << 6) + l];
    };
    auto PROC = [&](f32x4* src) {
        float d2 = 0.f;
        #pragma unroll
        for (int j = 0; j < 12; ++j) {
            f32x4 xv = xr[(j << 6) + l];
            float a0 = xv[0]-src[j][0], a1 = xv[1]-src[j][1],
                  a2 = xv[2]-src[j][2], a3 = xv[3]-src[j][3];
            d2 += a0*a0 + a1*a1 + a2*a2 + a3*a3;
        }
        #pragma unroll
        for (int off = 1; off < 64; off <<= 1) d2 += __shfl_xor(d2, off, 64);
        float s = d2 * isc;
        float mn = fmaxf(m, s);
        float f = __expf(m - mn);
        float wi = __expf(s - mn);
        #pragma unroll
        for (int j = 0; j < 12; ++j) o[j] = o[j] * f + wi * src[j];
        ll = ll * f + wi;
        m = mn;
    };

    int i = w;
    if (i < c) LD(A, i);
    for (; i < c; i += 16) {
        int i2 = i + 8;
        if (i2 < c) LD(Bv, i2);
        PROC(A);
        if (i2 < c) {
            if (i + 16 < c) LD(A, i + 16);
            PROC(Bv);
        }
    }
    om[w] = m; ol[w] = ll;
    __syncthreads();
    float M = om[0];
    #pragma unroll
    for (int ww = 1; ww < 8; ++ww) M = fmaxf(M, om[ww]);
    float Ls = 0.f;
    #pragma unroll
    for (int ww = 0; ww < 8; ++ww) Ls += ol[ww] * __expf(om[ww] - M);
    const float fw = __expf(m - M);
    f32x4* sv = (f32x4*)sumv;
    if (w == 0) {
        #pragma unroll
        for (int j = 0; j < 12; ++j) sv[(j << 6) + l] = o[j] * fw;
    }
    __syncthreads();
    for (int ww = 1; ww < 8; ++ww) {
        if (w == ww) {
            #pragma unroll
            for (int j = 0; j < 12; ++j) sv[(j << 6) + l] += o[j] * fw;
        }
        __syncthreads();
    }
    const float inv = 1.f / Ls;
    f32x4* od = (f32x4*)(out + (size_t)b * DD);
    for (int t = tid; t < 768; t += 512) od[t] = sv[t] * inv;
}

extern "C" void kernel_launch(void* const* d_in, const int* in_sizes, int n_in,
                              void* d_out, int out_size, void* d_ws, size_t ws_size,
                              hipStream_t stream) {
    const float* x   = (const float*)d_in[0];
    const float* sig = (const float*)d_in[1];
    const float* y   = (const float*)d_in[2];
    float* out = (float*)d_out;
    char* ws = (char*)d_ws;
    f16*   xp   = (f16*)(ws);                   // 1,572,864
    float* pmax = (float*)(ws + 1572864);       // 256*782*4 = 800,768
    f16*   S    = (f16*)(ws + 2373632);         // 256*50048*2 = 25,624,576

    kx  <<<384, 256, 0, stream>>>(x, xp);
    kqk <<<NBLK, 512, 0, stream>>>(xp, y, S, pmax);
    ksp <<<256, 512, 0, stream>>>(x, y, S, pmax, sig, out);
}